// Round 5
// baseline (546.400 us; speedup 1.0000x reference)
//
#include <hip/hip_runtime.h>

// ---------------------------------------------------------------------------
// EncoderDecoderAttentionHead. All GEMMs as A[M,K] @ B[N,K]^T, bf16 MFMA.
// R5: A-operand staged via global_load_lds ring-4 (paired-row XOR swizzle);
// B-operand loaded DIRECT global->register (double-buffered 2 tiles ahead,
// issued post-MFMA) -- removes B from LDS, halving LDS port pressure.
// One barrier + one counted vmcnt per K-tile (BK=32). 8 waves (2Mx4N).
// ---------------------------------------------------------------------------

typedef __attribute__((ext_vector_type(8))) __bf16 bf16x8;
typedef __attribute__((ext_vector_type(4))) float f32x4;
typedef __attribute__((ext_vector_type(4))) unsigned short ushort4v;
typedef __attribute__((ext_vector_type(8))) unsigned short ushort8v;

#define S_DIM 4096
#define T_DIM 4096
#define D_DIM 2048

__device__ __forceinline__ unsigned short f2bf(float f) {
    unsigned int u = __float_as_uint(f);
    u += 0x7fffu + ((u >> 16) & 1u);
    return (unsigned short)(u >> 16);
}

__device__ __forceinline__ void block_sync() {
    __builtin_amdgcn_sched_barrier(0);
    __builtin_amdgcn_s_barrier();
    __builtin_amdgcn_sched_barrier(0);
}

#define GL(gptr, sptr)                                                        \
    __builtin_amdgcn_global_load_lds(                                         \
        (__attribute__((address_space(1))) void*)(void*)(gptr),               \
        (__attribute__((address_space(3))) void*)(sptr), 16, 0, 0)

__device__ __forceinline__ f32x4 MFMA(bf16x8 a, bf16x8 b, f32x4 c) {
    return __builtin_amdgcn_mfma_f32_16x16x32_bf16(a, b, c, 0, 0, 0);
}

// ---- f32 -> bf16 convert ---------------------------------------------------
__global__ __launch_bounds__(256)
void k_convert(const float* __restrict__ in, unsigned short* __restrict__ out, long n) {
    long i = ((long)blockIdx.x * blockDim.x + threadIdx.x) * 8;
    const long stride = (long)gridDim.x * blockDim.x * 8;
    for (; i < n; i += stride) {
        float4 a = *(const float4*)(in + i);
        float4 b = *(const float4*)(in + i + 4);
        ushort8v o;
        o[0] = f2bf(a.x); o[1] = f2bf(a.y); o[2] = f2bf(a.z); o[3] = f2bf(a.w);
        o[4] = f2bf(b.x); o[5] = f2bf(b.y); o[6] = f2bf(b.z); o[7] = f2bf(b.w);
        *(ushort8v*)(out + i) = o;
    }
}

// ---- transpose f32 [R][C] -> bf16 [C][R] -----------------------------------
__global__ __launch_bounds__(256)
void k_transpose(const float* __restrict__ in, unsigned short* __restrict__ out,
                 int R, int C) {
    __shared__ float tile[32][33];
    const int bx = blockIdx.x * 32;
    const int by = blockIdx.y * 32;
    const int tx = threadIdx.x;
    const int ty = threadIdx.y;
    #pragma unroll
    for (int i = 0; i < 32; i += 8)
        tile[ty + i][tx] = in[(long)(by + ty + i) * C + bx + tx];
    __syncthreads();
    #pragma unroll
    for (int i = 0; i < 32; i += 8)
        out[(long)(bx + ty + i) * R + by + tx] = f2bf(tile[tx][ty + i]);
}

// ---- transpose bf16 [R][C] -> bf16 [C][R] ----------------------------------
__global__ __launch_bounds__(256)
void k_transpose_bf(const unsigned short* __restrict__ in,
                    unsigned short* __restrict__ out, int R, int C) {
    __shared__ unsigned short tile[32][33];
    const int bx = blockIdx.x * 32;
    const int by = blockIdx.y * 32;
    const int tx = threadIdx.x;
    const int ty = threadIdx.y;
    #pragma unroll
    for (int i = 0; i < 32; i += 8)
        tile[ty + i][tx] = in[(long)(by + ty + i) * C + bx + tx];
    __syncthreads();
    #pragma unroll
    for (int i = 0; i < 32; i += 8)
        out[(long)(bx + ty + i) * R + by + tx] = tile[tx][ty + i];
}

// ---- one pipeline segment (= one K-tile of 32) ------------------------------
// MFMA tile t from regs (au, bu [+a47 read here from cur]); prefetch A-frags
// of tile t+1 from nxt into af; reload bu with B(t+2) direct from global;
// stage A(t+3) into stg; counted vmcnt; barrier.
template<int MFR, bool DOSTG, bool DOB, int WVM, bool DOBAR, bool DOREAD, int LPTA>
__device__ __forceinline__ void seg_t(
    const unsigned short* (&gA)[2], const int (&ldA)[2],
    const unsigned short* const (&gB)[4],
    char* cur, char* nxt, char* stg, int arB, long kOffB,
    bf16x8 (&au)[4], bf16x8 (&af)[4], bf16x8 (&bu)[4],
    f32x4 (&acc)[MFR][4])
{
    bf16x8 a47[4];
    if constexpr (MFR == 8) {
        #pragma unroll
        for (int j = 0; j < 4; ++j)
            a47[j] = *(const bf16x8*)(cur + arB + (4 + j) * 1024);
    }
    if constexpr (DOREAD) {
        #pragma unroll
        for (int m = 0; m < 4; ++m)
            af[m] = *(const bf16x8*)(nxt + arB + m * 1024);
    }
    // wait: au (prefetched last segment) complete; newer ds_reads in flight
    if constexpr (MFR == 8) {
        if constexpr (DOREAD) asm volatile("s_waitcnt lgkmcnt(8)" ::: "memory");
        else                  asm volatile("s_waitcnt lgkmcnt(4)" ::: "memory");
    } else {
        if constexpr (DOREAD) asm volatile("s_waitcnt lgkmcnt(4)" ::: "memory");
        else                  asm volatile("s_waitcnt lgkmcnt(0)" ::: "memory");
    }
    __builtin_amdgcn_sched_barrier(0);
    __builtin_amdgcn_s_setprio(1);
    #pragma unroll
    for (int m = 0; m < 4; ++m)
        #pragma unroll
        for (int n = 0; n < 4; ++n)
            acc[m][n] = MFMA(au[m], bu[n], acc[m][n]);
    if constexpr (MFR == 8) {
        if constexpr (DOREAD) asm volatile("s_waitcnt lgkmcnt(4)" ::: "memory");
        else                  asm volatile("s_waitcnt lgkmcnt(0)" ::: "memory");
        __builtin_amdgcn_sched_barrier(0);
        #pragma unroll
        for (int j = 0; j < 4; ++j)
            #pragma unroll
            for (int n = 0; n < 4; ++n)
                acc[4 + j][n] = MFMA(a47[j], bu[n], acc[4 + j][n]);
    }
    __builtin_amdgcn_s_setprio(0);
    if constexpr (DOB) {          // reload bu with B(t+2); WAR on bu keeps order
        #pragma unroll
        for (int n = 0; n < 4; ++n)
            bu[n] = *(const bf16x8*)(gB[n] + kOffB);
    }
    if constexpr (DOSTG) {
        #pragma unroll
        for (int j = 0; j < LPTA; ++j) { GL(gA[j], stg + ldA[j]); gA[j] += 32; }
    }
    if constexpr (WVM == 6)      asm volatile("s_waitcnt vmcnt(6)" ::: "memory");
    else if constexpr (WVM == 5) asm volatile("s_waitcnt vmcnt(5)" ::: "memory");
    else if constexpr (WVM == 4) asm volatile("s_waitcnt vmcnt(4)" ::: "memory");
    else if constexpr (WVM == 0) asm volatile("s_waitcnt vmcnt(0)" ::: "memory");
    if constexpr (DOBAR) block_sync();
}

// ---- pipelined bf16 GEMM, C[M,N] = alpha*A[M,K]@B[N,K]^T (+bias[col]) ------
// BM = MFR*32, BN = 256, BK = 32, 8 waves (2 x 4), wave tile (MFR*16) x 64.
// A LDS granule (R,s): global (row = 2R+(c'&1), chunk8 = c'>>1), c' = s^(R&7).
template<int MFR, int OUT_BF16, int HAS_BIAS>
__global__ __launch_bounds__(512, 2)
void k_gemm(const unsigned short* __restrict__ A,
            const unsigned short* __restrict__ B,
            const float* __restrict__ bias,
            void* __restrict__ C,
            int M, int N, int K, float alpha) {
    constexpr int BM    = MFR * 32;
    constexpr int AGRAN = BM * 4;            // 16B granules in A tile
    constexpr int LPTA  = AGRAN / 512;       // A loads/thread/tile (2 or 1)
    constexpr int SLOT  = AGRAN * 16;        // A-only slot (16KB or 8KB)
    extern __shared__ __align__(16) char smem[];

    const int tid = threadIdx.x;
    const int l = tid & 63;
    const int w = tid >> 6;
    const int wr = w >> 2;                   // 0..1
    const int wc = w & 3;                    // 0..3

    // XCD-chunked + 4-col supertile block swizzle (grid always 256, gx%4==0)
    const int gx = gridDim.x, gy = gridDim.y;
    const int flat = blockIdx.y * gx + blockIdx.x;
    const int per = (gx * gy) >> 3;
    const int wid = (flat & 7) * per + (flat >> 3);
    const int sc = wid / (gy * 4);
    const int rm = wid - sc * gy * 4;
    const int by = rm >> 2;
    const int bx = sc * 4 + (rm & 3);

    const long brow = (long)by * BM;
    const long bcol = (long)bx * 256;
    const int NT = K >> 5;

    // A staging slots
    const unsigned short* gA[2];
    int ldA[2];
    #pragma unroll
    for (int j = 0; j < LPTA; ++j) {
        const int q = (w * LPTA + j) * 64 + l;
        const int R = q >> 3, s = q & 7, cp = s ^ (R & 7);
        gA[j] = A + (brow + 2 * R + (cp & 1)) * (long)K + (cp >> 1) * 8;
        ldA[j] = q * 16;
    }
    // B direct-load bases: frag n -> row bcol + wc*64 + n*16 + (l&15),
    // chunk (l>>4)*8; the wave covers 16 rows x 64B contiguous per frag.
    const unsigned short* gB[4];
    #pragma unroll
    for (int n = 0; n < 4; ++n)
        gB[n] = B + (bcol + wc * 64 + n * 16 + (l & 15)) * (long)K + (l >> 4) * 8;

    // A ds_read base (swizzled, lane-constant)
    const int sAB = ((((l >> 4) << 1) | (l & 1)) ^ ((l & 15) >> 1)) << 4;
    const int arB = (wr * (MFR * 8) + ((l & 15) >> 1)) * 128 + sAB;

    char* P0 = smem;
    char* P1 = smem + SLOT;
    char* P2 = smem + 2 * SLOT;
    char* P3 = smem + 3 * SLOT;

    f32x4 acc[MFR][4] = {};
    bf16x8 aE[4], aO[4], bE[4], bO[4];

    // prologue: stage A tiles 0,1,2; load B(0)->bE, B(1)->bO; preload A(0)
    {
        char* d = smem;
        #pragma unroll
        for (int tt = 0; tt < 3; ++tt) {
            #pragma unroll
            for (int j = 0; j < LPTA; ++j) { GL(gA[j], d + ldA[j]); gA[j] += 32; }
            d += SLOT;
        }
        __builtin_amdgcn_sched_barrier(0);   // keep B loads after the stages
        #pragma unroll
        for (int n = 0; n < 4; ++n) bE[n] = *(const bf16x8*)(gB[n]);
        #pragma unroll
        for (int n = 0; n < 4; ++n) bO[n] = *(const bf16x8*)(gB[n] + 32);
        asm volatile("s_waitcnt vmcnt(4)" ::: "memory");   // stages + bE done
        block_sync();
        #pragma unroll
        for (int m = 0; m < 4; ++m) aE[m] = *(const bf16x8*)(P0 + arB + m * 1024);
    }

    constexpr int WST = 4 + LPTA;            // steady-state vmcnt (6 or 5)
    for (int t = 0; t + 6 <= NT; t += 2) {
        seg_t<MFR, true, true, WST, true, true, LPTA>(
            gA, ldA, gB, P0, P1, P3, arB, (long)(t + 2) << 5, aE, aO, bE, acc);
        seg_t<MFR, true, true, WST, true, true, LPTA>(
            gA, ldA, gB, P1, P2, P0, arB, (long)(t + 3) << 5, aO, aE, bO, acc);
        char* tp = P0; P0 = P2; P2 = tp;
        tp = P1; P1 = P3; P3 = tp;
    }
    // tail: tiles NT-4 .. NT-1
    seg_t<MFR, true,  true,  WST, true, true, LPTA>(
        gA, ldA, gB, P0, P1, P3, arB, (long)(NT - 2) << 5, aE, aO, bE, acc);
    seg_t<MFR, false, true,  4,   true, true, LPTA>(
        gA, ldA, gB, P1, P2, P0, arB, (long)(NT - 1) << 5, aO, aE, bO, acc);
    seg_t<MFR, false, false, 0,   true, true, LPTA>(
        gA, ldA, gB, P2, P3, P1, arB, 0, aE, aO, bE, acc);
    seg_t<MFR, false, false, -1,  false, false, LPTA>(
        gA, ldA, gB, P3, P0, P2, arB, 0, aO, aE, bO, acc);

    // epilogue: C/D layout col = lane&15, row = (lane>>4)*4 + reg
    const long crow0 = brow + wr * (MFR * 16) + (l >> 4) * 4;
    const long ccol0 = bcol + wc * 64 + (l & 15);
    #pragma unroll
    for (int n = 0; n < 4; ++n) {
        const long col = ccol0 + n * 16;
        const float bb = HAS_BIAS ? bias[col] : 0.0f;
        #pragma unroll
        for (int m = 0; m < MFR; ++m) {
            #pragma unroll
            for (int r = 0; r < 4; ++r) {
                const long row = crow0 + m * 16 + r;
                const float v = acc[m][n][r] * alpha + bb;
                if (OUT_BF16)
                    ((unsigned short*)C)[row * N + col] = f2bf(v);
                else
                    ((float*)C)[row * N + col] = v;
            }
        }
    }
}

// ---- row softmax: e [S][T] f32 -> a [S][T] bf16 -----------------------------
__global__ __launch_bounds__(256)
void k_softmax(const float* __restrict__ E, unsigned short* __restrict__ A, int T) {
    const long row = blockIdx.x;
    const float* er = E + row * (long)T;
    const int t = threadIdx.x;
    const int l = t & 63;
    const int w = t >> 6;

    float4 v[4];
    float m = -3.4e38f;
    #pragma unroll
    for (int j = 0; j < 4; ++j) {
        v[j] = *(const float4*)(er + j * 1024 + t * 4);
        m = fmaxf(m, fmaxf(fmaxf(v[j].x, v[j].y), fmaxf(v[j].z, v[j].w)));
    }
    #pragma unroll
    for (int o = 32; o > 0; o >>= 1) m = fmaxf(m, __shfl_xor(m, o));

    __shared__ float redm[4];
    __shared__ float reds[4];
    if (l == 0) redm[w] = m;
    __syncthreads();
    m = fmaxf(fmaxf(redm[0], redm[1]), fmaxf(redm[2], redm[3]));

    float s = 0.f;
    #pragma unroll
    for (int j = 0; j < 4; ++j) {
        v[j].x = __expf(v[j].x - m); s += v[j].x;
        v[j].y = __expf(v[j].y - m); s += v[j].y;
        v[j].z = __expf(v[j].z - m); s += v[j].z;
        v[j].w = __expf(v[j].w - m); s += v[j].w;
    }
    #pragma unroll
    for (int o = 32; o > 0; o >>= 1) s += __shfl_xor(s, o);
    if (l == 0) reds[w] = s;
    __syncthreads();
    s = reds[0] + reds[1] + reds[2] + reds[3];
    const float inv = 1.0f / s;

    unsigned short* ar = A + row * (long)T;
    #pragma unroll
    for (int j = 0; j < 4; ++j) {
        ushort4v o4;
        o4[0] = f2bf(v[j].x * inv);
        o4[1] = f2bf(v[j].y * inv);
        o4[2] = f2bf(v[j].z * inv);
        o4[3] = f2bf(v[j].w * inv);
        *(ushort4v*)(ar + j * 1024 + t * 4) = o4;
    }
}

// ---------------------------------------------------------------------------
extern "C" void kernel_launch(void* const* d_in, const int* in_sizes, int n_in,
                              void* d_out, int out_size, void* d_ws, size_t ws_size,
                              hipStream_t stream) {
    const float* x   = (const float*)d_in[0];   // [S][D]
    const float* enc = (const float*)d_in[1];   // [2][T][S]
    const float* Wq  = (const float*)d_in[2];   // [D][D]
    const float* bq  = (const float*)d_in[3];   // [D]
    float* out = (float*)d_out;                 // [S][D]
    char* ws = (char*)d_ws;

    // abf overlaps xT/xbf (dead before softmax). Total footprint 168 MB.
    unsigned short* abf   = (unsigned short*)(ws);                 // [S][T]   32MB (late)
    unsigned short* xT    = (unsigned short*)(ws);                 // [D][S]   16MB (early)
    unsigned short* xbf   = (unsigned short*)(ws + (16L << 20));   // [S][D]   16MB (early)
    unsigned short* wqbf  = (unsigned short*)(ws + (32L << 20));   // [D][D]    8MB
    unsigned short* qbf   = (unsigned short*)(ws + (40L << 20));   // [S][D]   16MB
    unsigned short* kv    = (unsigned short*)(ws + (56L << 20));   // [2T][D]  32MB
    unsigned short* vT    = (unsigned short*)(ws + (88L << 20));   // [D][T]   16MB
    unsigned short* encbf = (unsigned short*)(ws + (104L << 20));  // [2][T][S] 64MB (early)
    float*          e     = (float*)(ws + (104L << 20));           // [S][T]   64MB (reuse)

    k_convert<<<4096, 256, 0, stream>>>(x,   xbf,   (long)S_DIM * D_DIM);
    k_convert<<<4096, 256, 0, stream>>>(Wq,  wqbf,  (long)D_DIM * D_DIM);
    k_convert<<<4096, 256, 0, stream>>>(enc, encbf, 2L * T_DIM * S_DIM);
    k_transpose<<<dim3(D_DIM / 32, S_DIM / 32), dim3(32, 8), 0, stream>>>(x, xT, S_DIM, D_DIM);

    #define LAUNCH_G(MFRV, OB, HB, Ap, Bp, biasp, Cp, M_, N_, K_, al)                      \
        do {                                                                               \
            constexpr int smemB = (MFRV * 32 * 64) * 4;                                    \
            hipFuncSetAttribute((const void*)k_gemm<MFRV, OB, HB>,                         \
                                hipFuncAttributeMaxDynamicSharedMemorySize, smemB);        \
            k_gemm<MFRV, OB, HB><<<dim3((N_) / 256, (M_) / (MFRV * 32)), 512, smemB,       \
                                   stream>>>(Ap, Bp, biasp, Cp, M_, N_, K_, al);           \
        } while (0)

    // q = x @ Wq^T + bq            [4096,2048]  grid (8,32)
    LAUNCH_G(4, 1, 1, xbf, wqbf, bq, qbf, S_DIM, D_DIM, D_DIM, 1.0f);
    // kv = enc @ xT^T (k rows 0..T-1, v rows T..2T-1)  [8192,2048]  grid (8,32)
    LAUNCH_G(8, 1, 0, encbf, xT, nullptr, kv, 2 * T_DIM, D_DIM, S_DIM, 1.0f);
    // vT = transpose(v)            [2048,4096]
    k_transpose_bf<<<dim3(D_DIM / 32, T_DIM / 32), dim3(32, 8), 0, stream>>>(
        kv + (long)T_DIM * D_DIM, vT, T_DIM, D_DIM);
    // e = q @ k^T / sqrt(D)        [4096,4096]  grid (16,16), fp32
    LAUNCH_G(8, 0, 0, qbf, kv, nullptr, e, S_DIM, T_DIM, D_DIM, 0.022097086912079608f);
    // a = softmax(e)               [S,T] bf16
    k_softmax<<<S_DIM, 256, 0, stream>>>(e, abf, T_DIM);
    // z = a @ vT^T                 [4096,2048]  grid (8,32), fp32 -> d_out
    LAUNCH_G(4, 0, 0, abf, vT, nullptr, out, S_DIM, D_DIM, T_DIM, 1.0f);
}

// Round 6
// 377.123 us; speedup vs baseline: 1.4489x; 1.4489x over previous
//
#include <hip/hip_runtime.h>

// ---------------------------------------------------------------------------
// EncoderDecoderAttentionHead. All GEMMs as A[M,K] @ B[N,K]^T, bf16 MFMA.
// R6: R4 ring-4 staging + m201-style phase split. BK=32, BN=256,
// BM=256 (MFR=8, two 16-MFMA phases/tile) or BM=128 (MFR=4, one phase).
// Conflict-free 64B-row swizzle: slot = chunk ^ ((row>>1)&3). Counted
// vmcnt/lgkmcnt, setprio around MFMA, XCD+supertile block swizzle.
// ---------------------------------------------------------------------------

typedef __attribute__((ext_vector_type(8))) __bf16 bf16x8;
typedef __attribute__((ext_vector_type(4))) float f32x4;
typedef __attribute__((ext_vector_type(4))) unsigned short ushort4v;
typedef __attribute__((ext_vector_type(8))) unsigned short ushort8v;

#define S_DIM 4096
#define T_DIM 4096
#define D_DIM 2048

__device__ __forceinline__ unsigned short f2bf(float f) {
    unsigned int u = __float_as_uint(f);
    u += 0x7fffu + ((u >> 16) & 1u);
    return (unsigned short)(u >> 16);
}

__device__ __forceinline__ void block_sync() {
    __builtin_amdgcn_sched_barrier(0);
    __builtin_amdgcn_s_barrier();
    __builtin_amdgcn_sched_barrier(0);
}

#define GL(gptr, sptr)                                                        \
    __builtin_amdgcn_global_load_lds(                                         \
        (__attribute__((address_space(1))) void*)(void*)(gptr),               \
        (__attribute__((address_space(3))) void*)(sptr), 16, 0, 0)

__device__ __forceinline__ f32x4 MFMA(bf16x8 a, bf16x8 b, f32x4 c) {
    return __builtin_amdgcn_mfma_f32_16x16x32_bf16(a, b, c, 0, 0, 0);
}

// ---- f32 -> bf16 convert ---------------------------------------------------
__global__ __launch_bounds__(256)
void k_convert(const float* __restrict__ in, unsigned short* __restrict__ out, long n) {
    long i = ((long)blockIdx.x * blockDim.x + threadIdx.x) * 8;
    const long stride = (long)gridDim.x * blockDim.x * 8;
    for (; i < n; i += stride) {
        float4 a = *(const float4*)(in + i);
        float4 b = *(const float4*)(in + i + 4);
        ushort8v o;
        o[0] = f2bf(a.x); o[1] = f2bf(a.y); o[2] = f2bf(a.z); o[3] = f2bf(a.w);
        o[4] = f2bf(b.x); o[5] = f2bf(b.y); o[6] = f2bf(b.z); o[7] = f2bf(b.w);
        *(ushort8v*)(out + i) = o;
    }
}

// ---- transpose f32 [R][C] -> bf16 [C][R] -----------------------------------
__global__ __launch_bounds__(256)
void k_transpose(const float* __restrict__ in, unsigned short* __restrict__ out,
                 int R, int C) {
    __shared__ float tile[32][33];
    const int bx = blockIdx.x * 32;
    const int by = blockIdx.y * 32;
    const int tx = threadIdx.x;
    const int ty = threadIdx.y;
    #pragma unroll
    for (int i = 0; i < 32; i += 8)
        tile[ty + i][tx] = in[(long)(by + ty + i) * C + bx + tx];
    __syncthreads();
    #pragma unroll
    for (int i = 0; i < 32; i += 8)
        out[(long)(bx + ty + i) * R + by + tx] = f2bf(tile[tx][ty + i]);
}

// ---- transpose bf16 [R][C] -> bf16 [C][R] ----------------------------------
__global__ __launch_bounds__(256)
void k_transpose_bf(const unsigned short* __restrict__ in,
                    unsigned short* __restrict__ out, int R, int C) {
    __shared__ unsigned short tile[32][33];
    const int bx = blockIdx.x * 32;
    const int by = blockIdx.y * 32;
    const int tx = threadIdx.x;
    const int ty = threadIdx.y;
    #pragma unroll
    for (int i = 0; i < 32; i += 8)
        tile[ty + i][tx] = in[(long)(by + ty + i) * C + bx + tx];
    __syncthreads();
    #pragma unroll
    for (int i = 0; i < 32; i += 8)
        out[(long)(bx + ty + i) * R + by + tx] = tile[tx][ty + i];
}

// ---- MFR=8 segment: one K-tile (BK=32), two phases of 16 MFMA ---------------
// P0: ds B23(cur); stage A(t+3); BAR; lgkm(2); MFMA n=0,1 (uses Ac,B01c)
// P1: ds A,B01(t+1 from nxt); stage B(t+3); vm; BAR; lgkm(10); MFMA n=2,3
template<bool STG, bool PF, int VMW>
__device__ __forceinline__ void seg8(
    const unsigned short* (&gA)[2], const int (&ldA)[2],
    const unsigned short* (&gB)[2], const int (&ldB)[2],
    const char* cur, const char* nxt, char* stg, int arB, int brB,
    bf16x8 (&Ac)[8], bf16x8 (&B01c)[2], bf16x8 (&B23)[2],
    bf16x8 (&An)[8], bf16x8 (&B01n)[2],
    f32x4 (&acc)[8][4])
{
    // ---------------- phase 0 ----------------
    B23[0] = *(const bf16x8*)(cur + brB + 2048);
    B23[1] = *(const bf16x8*)(cur + brB + 3072);
    if constexpr (STG) {
        GL(gA[0], stg + ldA[0]); gA[0] += 32;
        GL(gA[1], stg + ldA[1]); gA[1] += 32;
    }
    block_sync();
    asm volatile("s_waitcnt lgkmcnt(2)" ::: "memory");
    __builtin_amdgcn_sched_barrier(0);
    __builtin_amdgcn_s_setprio(1);
    #pragma unroll
    for (int m = 0; m < 8; ++m) {
        acc[m][0] = MFMA(Ac[m], B01c[0], acc[m][0]);
        acc[m][1] = MFMA(Ac[m], B01c[1], acc[m][1]);
    }
    __builtin_amdgcn_s_setprio(0);
    // ---------------- phase 1 ----------------
    if constexpr (PF) {
        #pragma unroll
        for (int m = 0; m < 8; ++m)
            An[m] = *(const bf16x8*)(nxt + arB + m * 1024);
        B01n[0] = *(const bf16x8*)(nxt + brB);
        B01n[1] = *(const bf16x8*)(nxt + brB + 1024);
    }
    if constexpr (STG) {
        GL(gB[0], stg + ldB[0]); gB[0] += 32;
        GL(gB[1], stg + ldB[1]); gB[1] += 32;
    }
    if constexpr (VMW == 4)      asm volatile("s_waitcnt vmcnt(4)" ::: "memory");
    else if constexpr (VMW == 0) asm volatile("s_waitcnt vmcnt(0)" ::: "memory");
    block_sync();
    if constexpr (PF) asm volatile("s_waitcnt lgkmcnt(10)" ::: "memory");
    else              asm volatile("s_waitcnt lgkmcnt(0)" ::: "memory");
    __builtin_amdgcn_sched_barrier(0);
    __builtin_amdgcn_s_setprio(1);
    #pragma unroll
    for (int m = 0; m < 8; ++m) {
        acc[m][2] = MFMA(Ac[m], B23[0], acc[m][2]);
        acc[m][3] = MFMA(Ac[m], B23[1], acc[m][3]);
    }
    __builtin_amdgcn_s_setprio(0);
}

// ---- MFR=4 segment: one K-tile, one 16-MFMA phase ---------------------------
template<bool STG, bool PF, int VMW>
__device__ __forceinline__ void seg4(
    const unsigned short* (&gA)[2], const int (&ldA)[2],
    const unsigned short* (&gB)[2], const int (&ldB)[2],
    const char* nxt, char* stg, int arB, int brB,
    bf16x8 (&Ac)[4], bf16x8 (&Bc)[4],
    bf16x8 (&An)[4], bf16x8 (&Bn)[4],
    f32x4 (&acc)[4][4])
{
    if constexpr (PF) {
        #pragma unroll
        for (int m = 0; m < 4; ++m)
            An[m] = *(const bf16x8*)(nxt + arB + m * 1024);
        #pragma unroll
        for (int n = 0; n < 4; ++n)
            Bn[n] = *(const bf16x8*)(nxt + brB + n * 1024);
    }
    if constexpr (STG) {
        GL(gA[0], stg + ldA[0]); gA[0] += 32;
        GL(gB[0], stg + ldB[0]); gB[0] += 32;
        GL(gB[1], stg + ldB[1]); gB[1] += 32;
    }
    if constexpr (VMW == 3)      asm volatile("s_waitcnt vmcnt(3)" ::: "memory");
    else if constexpr (VMW == 0) asm volatile("s_waitcnt vmcnt(0)" ::: "memory");
    block_sync();
    if constexpr (PF) asm volatile("s_waitcnt lgkmcnt(8)" ::: "memory");
    else              asm volatile("s_waitcnt lgkmcnt(0)" ::: "memory");
    __builtin_amdgcn_sched_barrier(0);
    __builtin_amdgcn_s_setprio(1);
    #pragma unroll
    for (int m = 0; m < 4; ++m)
        #pragma unroll
        for (int n = 0; n < 4; ++n)
            acc[m][n] = MFMA(Ac[m], Bc[n], acc[m][n]);
    __builtin_amdgcn_s_setprio(0);
}

// ---- pipelined bf16 GEMM, C[M,N] = alpha*A[M,K]@B[N,K]^T (+bias[col]) ------
// BM = MFR*32, BN = 256, BK = 32, 8 waves (2Mx4N), wave tile (MFR*16)x64.
// LDS rows are 64B (one K-tile row); granule (R,s) holds chunk s^((R>>1)&3).
template<int MFR, int OUT_BF16, int HAS_BIAS>
__global__ __launch_bounds__(512, 2)
void k_gemm(const unsigned short* __restrict__ A,
            const unsigned short* __restrict__ B,
            const float* __restrict__ bias,
            void* __restrict__ C,
            int M, int N, int K, float alpha) {
    constexpr int BM   = MFR * 32;
    constexpr int LPTA = (BM * 4) / 512;     // A gloads/thread/tile (2 or 1)
    constexpr int LDSA = BM * 64;            // A region bytes (rows of 64B)
    constexpr int SLOT = LDSA + 16384;       // + B region (256 rows x 64B)
    extern __shared__ __align__(16) char smem[];

    const int tid = threadIdx.x;
    const int l = tid & 63;
    const int w = tid >> 6;
    const int wr = w >> 2;                   // 0..1
    const int wc = w & 3;                    // 0..3

    // XCD-chunked + 4-col supertile block swizzle (grid always 256, gx%4==0)
    const int gx = gridDim.x, gy = gridDim.y;
    const int flat = blockIdx.y * gx + blockIdx.x;
    const int per = (gx * gy) >> 3;
    const int wid = (flat & 7) * per + (flat >> 3);
    const int sc = wid / (gy * 4);
    const int rm = wid - sc * gy * 4;
    const int by = rm >> 2;
    const int bx = sc * 4 + (rm & 3);

    const long brow = (long)by * BM;
    const long bcol = (long)bx * 256;
    const int NT = K >> 5;

    // staging: granule q -> LDS byte q*16; row R=q>>2, slot s=q&3,
    // source chunk c = s ^ ((R>>1)&3)
    const unsigned short* gA[2];
    int ldA[2];
    #pragma unroll
    for (int j = 0; j < LPTA; ++j) {
        const int q = (w * LPTA + j) * 64 + l;
        const int R = q >> 2;
        const int c = (q & 3) ^ ((R >> 1) & 3);
        gA[j] = A + (brow + R) * (long)K + c * 8;
        ldA[j] = q * 16;
    }
    const unsigned short* gB[2];
    int ldB[2];
    #pragma unroll
    for (int j = 0; j < 2; ++j) {
        const int q = (w * 2 + j) * 64 + l;
        const int R = q >> 2;
        const int c = (q & 3) ^ ((R >> 1) & 3);
        gB[j] = B + (bcol + R) * (long)K + c * 8;
        ldB[j] = LDSA + q * 16;
    }

    // ds_read bases: frag row = base + (l&15), chunk = l>>4,
    // byte = row*64 + ((chunk ^ ((row>>1)&3))<<4); frag step = 16 rows = 1024B
    const int sAB = (((l >> 4) ^ ((l >> 1) & 3)) << 4);
    const int arB = (wr * (MFR * 16) + (l & 15)) * 64 + sAB;
    const int brB = LDSA + (wc * 64 + (l & 15)) * 64 + sAB;

    char* const b0 = smem;
    char* const b1 = smem + SLOT;
    char* const b2 = smem + 2 * SLOT;
    char* const b3 = smem + 3 * SLOT;

    f32x4 acc[MFR][4] = {};

    // prologue: stage tiles 0,1,2 into slots 0,1,2; ensure 0 AND 1 landed
    {
        char* d = smem;
        #pragma unroll
        for (int tt = 0; tt < 3; ++tt) {
            #pragma unroll
            for (int j = 0; j < LPTA; ++j) { GL(gA[j], d + ldA[j]); gA[j] += 32; }
            #pragma unroll
            for (int j = 0; j < 2; ++j)    { GL(gB[j], d + ldB[j]); gB[j] += 32; }
            d += SLOT;
        }
        if constexpr (MFR == 8) asm volatile("s_waitcnt vmcnt(4)" ::: "memory");
        else                    asm volatile("s_waitcnt vmcnt(3)" ::: "memory");
        block_sync();
    }

    if constexpr (MFR == 8) {
        bf16x8 Aa[8], Ab[8], Ba[2], Bb[2], B23[2];
        #pragma unroll
        for (int m = 0; m < 8; ++m) Aa[m] = *(const bf16x8*)(b0 + arB + m * 1024);
        Ba[0] = *(const bf16x8*)(b0 + brB);
        Ba[1] = *(const bf16x8*)(b0 + brB + 1024);

        for (int t = 0; t + 8 <= NT; t += 4) {
            seg8<true, true, 4>(gA, ldA, gB, ldB, b0, b1, b3, arB, brB,
                                Aa, Ba, B23, Ab, Bb, acc);
            seg8<true, true, 4>(gA, ldA, gB, ldB, b1, b2, b0, arB, brB,
                                Ab, Bb, B23, Aa, Ba, acc);
            seg8<true, true, 4>(gA, ldA, gB, ldB, b2, b3, b1, arB, brB,
                                Aa, Ba, B23, Ab, Bb, acc);
            seg8<true, true, 4>(gA, ldA, gB, ldB, b3, b0, b2, arB, brB,
                                Ab, Bb, B23, Aa, Ba, acc);
        }
        // tail: tiles NT-4 .. NT-1
        seg8<true,  true,  4>(gA, ldA, gB, ldB, b0, b1, b3, arB, brB,
                              Aa, Ba, B23, Ab, Bb, acc);
        seg8<false, true,  0>(gA, ldA, gB, ldB, b1, b2, b3, arB, brB,
                              Ab, Bb, B23, Aa, Ba, acc);
        seg8<false, true, -1>(gA, ldA, gB, ldB, b2, b3, b3, arB, brB,
                              Aa, Ba, B23, Ab, Bb, acc);
        seg8<false, false, -1>(gA, ldA, gB, ldB, b3, b0, b3, arB, brB,
                               Ab, Bb, B23, Aa, Ba, acc);
    } else {
        bf16x8 Aa[4], Ab[4], Ba[4], Bb[4];
        #pragma unroll
        for (int m = 0; m < 4; ++m) Aa[m] = *(const bf16x8*)(b0 + arB + m * 1024);
        #pragma unroll
        for (int n = 0; n < 4; ++n) Ba[n] = *(const bf16x8*)(b0 + brB + n * 1024);

        for (int t = 0; t + 8 <= NT; t += 4) {
            seg4<true, true, 3>(gA, ldA, gB, ldB, b1, b3, arB, brB, Aa, Ba, Ab, Bb, acc);
            seg4<true, true, 3>(gA, ldA, gB, ldB, b2, b0, arB, brB, Ab, Bb, Aa, Ba, acc);
            seg4<true, true, 3>(gA, ldA, gB, ldB, b3, b1, arB, brB, Aa, Ba, Ab, Bb, acc);
            seg4<true, true, 3>(gA, ldA, gB, ldB, b0, b2, arB, brB, Ab, Bb, Aa, Ba, acc);
        }
        seg4<true,  true,  3>(gA, ldA, gB, ldB, b1, b3, arB, brB, Aa, Ba, Ab, Bb, acc);
        seg4<false, true,  0>(gA, ldA, gB, ldB, b2, b3, arB, brB, Ab, Bb, Aa, Ba, acc);
        seg4<false, true, -1>(gA, ldA, gB, ldB, b3, b3, arB, brB, Aa, Ba, Ab, Bb, acc);
        seg4<false, false, -1>(gA, ldA, gB, ldB, b3, b3, arB, brB, Ab, Bb, Aa, Ba, acc);
    }

    // epilogue: C/D layout col = lane&15, row = (lane>>4)*4 + reg
    const long crow0 = brow + wr * (MFR * 16) + (l >> 4) * 4;
    const long ccol0 = bcol + wc * 64 + (l & 15);
    #pragma unroll
    for (int n = 0; n < 4; ++n) {
        const long col = ccol0 + n * 16;
        const float bb = HAS_BIAS ? bias[col] : 0.0f;
        #pragma unroll
        for (int m = 0; m < MFR; ++m) {
            #pragma unroll
            for (int r = 0; r < 4; ++r) {
                const long row = crow0 + m * 16 + r;
                const float v = acc[m][n][r] * alpha + bb;
                if (OUT_BF16)
                    ((unsigned short*)C)[row * N + col] = f2bf(v);
                else
                    ((float*)C)[row * N + col] = v;
            }
        }
    }
}

// ---- row softmax: e [S][T] f32 -> a [S][T] bf16 -----------------------------
__global__ __launch_bounds__(256)
void k_softmax(const float* __restrict__ E, unsigned short* __restrict__ A, int T) {
    const long row = blockIdx.x;
    const float* er = E + row * (long)T;
    const int t = threadIdx.x;
    const int l = t & 63;
    const int w = t >> 6;

    float4 v[4];
    float m = -3.4e38f;
    #pragma unroll
    for (int j = 0; j < 4; ++j) {
        v[j] = *(const float4*)(er + j * 1024 + t * 4);
        m = fmaxf(m, fmaxf(fmaxf(v[j].x, v[j].y), fmaxf(v[j].z, v[j].w)));
    }
    #pragma unroll
    for (int o = 32; o > 0; o >>= 1) m = fmaxf(m, __shfl_xor(m, o));

    __shared__ float redm[4];
    __shared__ float reds[4];
    if (l == 0) redm[w] = m;
    __syncthreads();
    m = fmaxf(fmaxf(redm[0], redm[1]), fmaxf(redm[2], redm[3]));

    float s = 0.f;
    #pragma unroll
    for (int j = 0; j < 4; ++j) {
        v[j].x = __expf(v[j].x - m); s += v[j].x;
        v[j].y = __expf(v[j].y - m); s += v[j].y;
        v[j].z = __expf(v[j].z - m); s += v[j].z;
        v[j].w = __expf(v[j].w - m); s += v[j].w;
    }
    #pragma unroll
    for (int o = 32; o > 0; o >>= 1) s += __shfl_xor(s, o);
    if (l == 0) reds[w] = s;
    __syncthreads();
    s = reds[0] + reds[1] + reds[2] + reds[3];
    const float inv = 1.0f / s;

    unsigned short* ar = A + row * (long)T;
    #pragma unroll
    for (int j = 0; j < 4; ++j) {
        ushort4v o4;
        o4[0] = f2bf(v[j].x * inv);
        o4[1] = f2bf(v[j].y * inv);
        o4[2] = f2bf(v[j].z * inv);
        o4[3] = f2bf(v[j].w * inv);
        *(ushort4v*)(ar + j * 1024 + t * 4) = o4;
    }
}

// ---------------------------------------------------------------------------
extern "C" void kernel_launch(void* const* d_in, const int* in_sizes, int n_in,
                              void* d_out, int out_size, void* d_ws, size_t ws_size,
                              hipStream_t stream) {
    const float* x   = (const float*)d_in[0];   // [S][D]
    const float* enc = (const float*)d_in[1];   // [2][T][S]
    const float* Wq  = (const float*)d_in[2];   // [D][D]
    const float* bq  = (const float*)d_in[3];   // [D]
    float* out = (float*)d_out;                 // [S][D]
    char* ws = (char*)d_ws;

    // abf overlaps xT/xbf (dead before softmax). Total footprint 168 MB.
    unsigned short* abf   = (unsigned short*)(ws);                 // [S][T]   32MB (late)
    unsigned short* xT    = (unsigned short*)(ws);                 // [D][S]   16MB (early)
    unsigned short* xbf   = (unsigned short*)(ws + (16L << 20));   // [S][D]   16MB (early)
    unsigned short* wqbf  = (unsigned short*)(ws + (32L << 20));   // [D][D]    8MB
    unsigned short* qbf   = (unsigned short*)(ws + (40L << 20));   // [S][D]   16MB
    unsigned short* kv    = (unsigned short*)(ws + (56L << 20));   // [2T][D]  32MB
    unsigned short* vT    = (unsigned short*)(ws + (88L << 20));   // [D][T]   16MB
    unsigned short* encbf = (unsigned short*)(ws + (104L << 20));  // [2][T][S] 64MB (early)
    float*          e     = (float*)(ws + (104L << 20));           // [S][T]   64MB (reuse)

    k_convert<<<4096, 256, 0, stream>>>(x,   xbf,   (long)S_DIM * D_DIM);
    k_convert<<<4096, 256, 0, stream>>>(Wq,  wqbf,  (long)D_DIM * D_DIM);
    k_convert<<<4096, 256, 0, stream>>>(enc, encbf, 2L * T_DIM * S_DIM);
    k_transpose<<<dim3(D_DIM / 32, S_DIM / 32), dim3(32, 8), 0, stream>>>(x, xT, S_DIM, D_DIM);

    #define LAUNCH_G(MFRV, OB, HB, Ap, Bp, biasp, Cp, M_, N_, K_, al)                      \
        do {                                                                               \
            constexpr int smemB = (MFRV * 32 * 64 + 16384) * 4;                            \
            hipFuncSetAttribute((const void*)k_gemm<MFRV, OB, HB>,                         \
                                hipFuncAttributeMaxDynamicSharedMemorySize, smemB);        \
            k_gemm<MFRV, OB, HB><<<dim3((N_) / 256, (M_) / (MFRV * 32)), 512, smemB,       \
                                   stream>>>(Ap, Bp, biasp, Cp, M_, N_, K_, al);           \
        } while (0)

    // q = x @ Wq^T + bq            [4096,2048]  grid (8,32)
    LAUNCH_G(4, 1, 1, xbf, wqbf, bq, qbf, S_DIM, D_DIM, D_DIM, 1.0f);
    // kv = enc @ xT^T (k rows 0..T-1, v rows T..2T-1)  [8192,2048]  grid (8,32)
    LAUNCH_G(8, 1, 0, encbf, xT, nullptr, kv, 2 * T_DIM, D_DIM, S_DIM, 1.0f);
    // vT = transpose(v)            [2048,4096]
    k_transpose_bf<<<dim3(D_DIM / 32, T_DIM / 32), dim3(32, 8), 0, stream>>>(
        kv + (long)T_DIM * D_DIM, vT, T_DIM, D_DIM);
    // e = q @ k^T / sqrt(D)        [4096,4096]  grid (16,16), fp32
    LAUNCH_G(8, 0, 0, qbf, kv, nullptr, e, S_DIM, T_DIM, D_DIM, 0.022097086912079608f);
    // a = softmax(e)               [S,T] bf16
    k_softmax<<<S_DIM, 256, 0, stream>>>(e, abf, T_DIM);
    // z = a @ vT^T                 [4096,2048]  grid (8,32), fp32 -> d_out
    LAUNCH_G(4, 0, 0, abf, vT, nullptr, out, S_DIM, D_DIM, T_DIM, 1.0f);
}